// Round 1
// baseline (1753.965 us; speedup 1.0000x reference)
//
#include <hip/hip_runtime.h>

#define NSAMP 65536
#define HID 256
#define MWG 8            // samples per workgroup
#define RROWS 48         // 6 channels * MWG
#define LDA 264          // padded LDS row stride (floats), 16B-aligned rows
#define MU_F 1.7894e-05f

// fast tanh via hardware exp: tanh(z) = 1 - 2/(exp(2z)+1); exact at +-inf limits
__device__ __forceinline__ float tanh_fast(float z) {
    float e = __expf(2.0f * z);
    return 1.0f - 2.0f / (e + 1.0f);
}

__global__ void zero_out_kernel(float* out) {
    if (threadIdx.x < 2) out[1 + threadIdx.x] = 0.0f;
}

__global__ void finalize_kernel(float* out) {
    if (threadIdx.x == 0) {
        float data = out[1] * (1.0f / (3.0f * (float)NSAMP));
        float phys = out[2] * (1.0f / (float)NSAMP);
        out[0] = data + phys;
        out[1] = data;
        out[2] = phys;
    }
}

// Rows in A: r = m*6 + ch, ch: 0=h, 1=t0, 2=t1, 3=t2, 4=s_ab, 5=s_c
// t_i  : first-order tangent along e_i (post-activation)
// s_ab : second-order (quadratic-form) channel along d=(2,2,1,0)
// s_c  : second-order channel along d=(0,0,1,0)
__global__ __launch_bounds__(256)
void pinn_loss_kernel(const float* __restrict__ x, const float* __restrict__ target,
                      const float* __restrict__ W0, const float* __restrict__ b0,
                      const float* __restrict__ W1, const float* __restrict__ b1,
                      const float* __restrict__ W2, const float* __restrict__ b2,
                      const float* __restrict__ W3, const float* __restrict__ b3,
                      const float* __restrict__ W4, const float* __restrict__ b4,
                      float* __restrict__ out_acc)
{
    __shared__ float A[RROWS][LDA];
    __shared__ float OUTS[RROWS][5];
    __shared__ float rsum[2];

    const int tid = threadIdx.x;
    const int base = blockIdx.x * MWG;

    // ---------------- layer 1: input(4) -> 256, direct elementwise init ----------------
    {
        const int j = tid;  // one column per thread
        const float w0 = W0[0 * HID + j];
        const float w1 = W0[1 * HID + j];
        const float w2 = W0[2 * HID + j];
        const float w3 = W0[3 * HID + j];
        const float bj = b0[j];
        const float tab = 2.0f * w0 + 2.0f * w1 + w2;   // pre-act tangent along (2,2,1,0)
        const float tab2 = tab * tab;
        const float tc2 = w2 * w2;                       // along (0,0,1,0)
        #pragma unroll
        for (int m = 0; m < MWG; ++m) {
            const float* xm = x + (size_t)(base + m) * 4;
            float x0 = xm[0], x1 = xm[1], x2 = xm[2], x3 = xm[3];
            float z = fmaf(x0, w0, fmaf(x1, w1, fmaf(x2, w2, fmaf(x3, w3, bj))));
            float h = tanh_fast(z);
            float up = 1.0f - h * h;
            float m2hu = -2.0f * h * up;
            A[m * 6 + 0][j] = h;
            A[m * 6 + 1][j] = up * w0;
            A[m * 6 + 2][j] = up * w1;
            A[m * 6 + 3][j] = up * w2;
            A[m * 6 + 4][j] = m2hu * tab2;   // sz=0 at first layer
            A[m * 6 + 5][j] = m2hu * tc2;
        }
    }
    __syncthreads();

    // ---------------- layers 2..4: GEMM (48x256 @ 256x256) + fused elementwise ----------------
    const int tj = tid & 63;     // column group: 64 groups of 4 columns
    const int tr = tid >> 6;     // row group (wave id): 4 groups of 12 rows (= 2 samples x 6 ch)
    const int j0 = tj * 4;
    const int r0 = tr * 12;

    const float* Wl[3] = {W1, W2, W3};
    const float* bl[3] = {b1, b2, b3};

    for (int l = 0; l < 3; ++l) {
        const float* __restrict__ W = Wl[l];
        float acc[12][4];
        #pragma unroll
        for (int r = 0; r < 12; ++r) {
            #pragma unroll
            for (int c = 0; c < 4; ++c) acc[r][c] = 0.0f;
        }

        for (int k = 0; k < HID; k += 4) {
            const float4 wv0 = *reinterpret_cast<const float4*>(W + (k + 0) * HID + j0);
            const float4 wv1 = *reinterpret_cast<const float4*>(W + (k + 1) * HID + j0);
            const float4 wv2 = *reinterpret_cast<const float4*>(W + (k + 2) * HID + j0);
            const float4 wv3 = *reinterpret_cast<const float4*>(W + (k + 3) * HID + j0);
            #pragma unroll
            for (int r = 0; r < 12; ++r) {
                const float4 av = *reinterpret_cast<const float4*>(&A[r0 + r][k]);
                acc[r][0] = fmaf(av.x, wv0.x, acc[r][0]);
                acc[r][1] = fmaf(av.x, wv0.y, acc[r][1]);
                acc[r][2] = fmaf(av.x, wv0.z, acc[r][2]);
                acc[r][3] = fmaf(av.x, wv0.w, acc[r][3]);
                acc[r][0] = fmaf(av.y, wv1.x, acc[r][0]);
                acc[r][1] = fmaf(av.y, wv1.y, acc[r][1]);
                acc[r][2] = fmaf(av.y, wv1.z, acc[r][2]);
                acc[r][3] = fmaf(av.y, wv1.w, acc[r][3]);
                acc[r][0] = fmaf(av.z, wv2.x, acc[r][0]);
                acc[r][1] = fmaf(av.z, wv2.y, acc[r][1]);
                acc[r][2] = fmaf(av.z, wv2.z, acc[r][2]);
                acc[r][3] = fmaf(av.z, wv2.w, acc[r][3]);
                acc[r][0] = fmaf(av.w, wv3.x, acc[r][0]);
                acc[r][1] = fmaf(av.w, wv3.y, acc[r][1]);
                acc[r][2] = fmaf(av.w, wv3.z, acc[r][2]);
                acc[r][3] = fmaf(av.w, wv3.w, acc[r][3]);
            }
        }
        __syncthreads();   // all GEMM reads of A complete before overwrite

        // elementwise tanh-chain entirely in registers:
        // thread owns samples {2*tr, 2*tr+1}, all 6 channels, cols j0..j0+3
        const float4 bv = *reinterpret_cast<const float4*>(bl[l] + j0);
        const float bArr[4] = {bv.x, bv.y, bv.z, bv.w};
        #pragma unroll
        for (int s = 0; s < 2; ++s) {
            float o[6][4];
            #pragma unroll
            for (int c = 0; c < 4; ++c) {
                float Z   = acc[s * 6 + 0][c] + bArr[c];
                float T0  = acc[s * 6 + 1][c];
                float T1  = acc[s * 6 + 2][c];
                float T2  = acc[s * 6 + 3][c];
                float Sab = acc[s * 6 + 4][c];
                float Sc  = acc[s * 6 + 5][c];
                float h  = tanh_fast(Z);
                float up = 1.0f - h * h;
                float tab = 2.0f * T0 + 2.0f * T1 + T2;
                float m2hu = -2.0f * h * up;
                o[0][c] = h;
                o[1][c] = up * T0;
                o[2][c] = up * T1;
                o[3][c] = up * T2;
                o[4][c] = fmaf(up, Sab, m2hu * tab * tab);
                o[5][c] = fmaf(up, Sc,  m2hu * T2 * T2);
            }
            #pragma unroll
            for (int ch = 0; ch < 6; ++ch) {
                *reinterpret_cast<float4*>(&A[(2 * tr + s) * 6 + ch][j0]) =
                    make_float4(o[ch][0], o[ch][1], o[ch][2], o[ch][3]);
            }
        }
        __syncthreads();
    }

    // ---------------- final layer: OUTS[48][5] = A @ W4 (+b4 on primal rows) ----------------
    if (tid < RROWS * 5) {
        const int r = tid / 5;
        const int c = tid - r * 5;
        float s = 0.0f;
        for (int k = 0; k < HID; k += 4) {
            const float4 av = *reinterpret_cast<const float4*>(&A[r][k]);
            s = fmaf(av.x, W4[(k + 0) * 5 + c], s);
            s = fmaf(av.y, W4[(k + 1) * 5 + c], s);
            s = fmaf(av.z, W4[(k + 2) * 5 + c], s);
            s = fmaf(av.w, W4[(k + 3) * 5 + c], s);
        }
        if (r % 6 == 0) s += b4[c];   // primal channel rows are r = m*6+0
        OUTS[r][c] = s;
    }
    if (tid == 0) { rsum[0] = 0.0f; rsum[1] = 0.0f; }
    __syncthreads();

    // ---------------- NS residuals + block reduction ----------------
    if (tid < MWG) {
        const int m = tid;
        const int rb = m * 6;
        float u   = OUTS[rb + 0][0];
        float v   = OUTS[rb + 0][1];
        float w_  = OUTS[rb + 0][2];
        float rho = OUTS[rb + 0][3];
        const float* tg = target + (size_t)(base + m) * 3;
        float d0 = u - tg[0], d1 = v - tg[1], d2 = w_ - tg[2];
        float dpart = d0 * d0 + d1 * d1 + d2 * d2;

        float ug0 = OUTS[rb + 1][0], vg0 = OUTS[rb + 1][1], wg0 = OUTS[rb + 1][2], pg0 = OUTS[rb + 1][4];
        float ug1 = OUTS[rb + 2][0], vg1 = OUTS[rb + 2][1], wg1 = OUTS[rb + 2][2], pg1 = OUTS[rb + 2][4];
        float ug2 = OUTS[rb + 3][0], vg2 = OUTS[rb + 3][1], wg2 = OUTS[rb + 3][2];

        // polarization: h_k[0]+h_k[1] = 1/4 * (q_ab[k] - q_c[k])
        float hu = 0.25f * (OUTS[rb + 4][0] - OUTS[rb + 5][0]);
        float hv = 0.25f * (OUTS[rb + 4][1] - OUTS[rb + 5][1]);
        float hw = 0.25f * (OUTS[rb + 4][2] - OUTS[rb + 5][2]);

        float mx = rho * (ug2 + u * ug0 + v * ug1) + pg0 - MU_F * hu;
        float my = rho * (vg2 + u * vg0 + v * vg1) + pg1 - MU_F * hv;
        float mz = rho * (wg2 + u * wg0 + v * wg1)       - MU_F * hw;
        float ppart = mx * mx + my * my + mz * mz;

        atomicAdd(&rsum[0], dpart);
        atomicAdd(&rsum[1], ppart);
    }
    __syncthreads();
    if (tid == 0) {
        atomicAdd(&out_acc[1], rsum[0]);
        atomicAdd(&out_acc[2], rsum[1]);
    }
}

extern "C" void kernel_launch(void* const* d_in, const int* in_sizes, int n_in,
                              void* d_out, int out_size, void* d_ws, size_t ws_size,
                              hipStream_t stream) {
    const float* x  = (const float*)d_in[0];
    const float* tg = (const float*)d_in[1];
    const float* W0 = (const float*)d_in[2];
    const float* b0 = (const float*)d_in[3];
    const float* W1 = (const float*)d_in[4];
    const float* b1 = (const float*)d_in[5];
    const float* W2 = (const float*)d_in[6];
    const float* b2 = (const float*)d_in[7];
    const float* W3 = (const float*)d_in[8];
    const float* b3 = (const float*)d_in[9];
    const float* W4 = (const float*)d_in[10];
    const float* b4 = (const float*)d_in[11];
    float* out = (float*)d_out;

    zero_out_kernel<<<dim3(1), dim3(64), 0, stream>>>(out);
    pinn_loss_kernel<<<dim3(NSAMP / MWG), dim3(256), 0, stream>>>(
        x, tg, W0, b0, W1, b1, W2, b2, W3, b3, W4, b4, out);
    finalize_kernel<<<dim3(1), dim3(64), 0, stream>>>(out);
}

// Round 2
// 398.064 us; speedup vs baseline: 4.4062x; 4.4062x over previous
//
#include <hip/hip_runtime.h>

#define NSAMP 65536
#define HID 256
#define MWG 8            // samples per workgroup
#define RROWS 48         // 6 channels * MWG
#define LDA 264          // padded LDS row stride (f16 elems): 528 B rows -> bank shift 4/row
#define MU_F 1.7894e-05f

typedef _Float16 half8 __attribute__((ext_vector_type(8)));
typedef float f32x4 __attribute__((ext_vector_type(4)));

// fast tanh via hardware exp: tanh(z) = 1 - 2/(exp(2z)+1)
__device__ __forceinline__ float tanh_fast(float z) {
    float e = __expf(2.0f * z);
    return 1.0f - 2.0f / (e + 1.0f);
}

__global__ void zero_out_kernel(float* out) {
    if (threadIdx.x < 2) out[1 + threadIdx.x] = 0.0f;
}

__global__ void finalize_kernel(float* out) {
    if (threadIdx.x == 0) {
        float data = out[1] * (1.0f / (3.0f * (float)NSAMP));
        float phys = out[2] * (1.0f / (float)NSAMP);
        out[0] = data + phys;
        out[1] = data;
        out[2] = phys;
    }
}

// Pack W1..W3 (fp32 256x256, row-major [k][col]) into f16 B-fragment order:
// idx = ((jt*8 + ks)*64 + lane)*8 + j  ->  W[k*256+col], k = ks*32 + (lane>>4)*8 + j,
// col = jt*16 + (lane&15).  One wave's (jt,ks) fragment load = lane*16B, coalesced.
__global__ __launch_bounds__(256)
void pack_w_kernel(const float* __restrict__ W1, const float* __restrict__ W2,
                   const float* __restrict__ W3, _Float16* __restrict__ ws) {
    const int gid = blockIdx.x * 256 + threadIdx.x;   // 0 .. 3*65536-1
    const int layer = gid >> 16;
    const int idx = gid & 65535;
    const int j    = idx & 7;
    const int lane = (idx >> 3) & 63;
    const int ks   = (idx >> 9) & 7;
    const int jt   = idx >> 12;
    const int k   = ks * 32 + (lane >> 4) * 8 + j;
    const int col = jt * 16 + (lane & 15);
    const float* W = (layer == 0) ? W1 : (layer == 1) ? W2 : W3;
    ws[gid] = (_Float16)W[k * HID + col];
}

// AD channel rows: r = m*6 + ch; ch: 0=h, 1=t0, 2=t1, 3=t2, 4=s_ab (dir 2,2,1,0), 5=s_c (dir 0,0,1,0)
__global__ __launch_bounds__(256, 3)
void pinn_loss_kernel(const float* __restrict__ x, const float* __restrict__ target,
                      const float* __restrict__ W0, const float* __restrict__ b0,
                      const float* __restrict__ b1, const float* __restrict__ b2,
                      const float* __restrict__ b3,
                      const float* __restrict__ W4, const float* __restrict__ b4,
                      const _Float16* __restrict__ Wp,   // packed f16 W1..W3 in d_ws
                      float* __restrict__ out_acc)
{
    __shared__ _Float16 buf[2][RROWS][LDA];   // ping-pong activation buffers (f16)
    __shared__ float OUTS[RROWS][5];
    __shared__ float rsum[2];

    const int tid = threadIdx.x;
    const int base = blockIdx.x * MWG;

    // ---------------- layer 1: input(4) -> 256, elementwise init ----------------
    {
        const int j = tid;
        const float w0 = W0[0 * HID + j];
        const float w1 = W0[1 * HID + j];
        const float w2 = W0[2 * HID + j];
        const float w3 = W0[3 * HID + j];
        const float bj = b0[j];
        const float tab = 2.0f * w0 + 2.0f * w1 + w2;
        const float tab2 = tab * tab;
        const float tc2 = w2 * w2;
        #pragma unroll
        for (int m = 0; m < MWG; ++m) {
            const float* xm = x + (size_t)(base + m) * 4;
            float z = fmaf(xm[0], w0, fmaf(xm[1], w1, fmaf(xm[2], w2, fmaf(xm[3], w3, bj))));
            float h = tanh_fast(z);
            float up = 1.0f - h * h;
            float m2hu = -2.0f * h * up;
            buf[0][m * 6 + 0][j] = (_Float16)h;
            buf[0][m * 6 + 1][j] = (_Float16)(up * w0);
            buf[0][m * 6 + 2][j] = (_Float16)(up * w1);
            buf[0][m * 6 + 3][j] = (_Float16)(up * w2);
            buf[0][m * 6 + 4][j] = (_Float16)(m2hu * tab2);
            buf[0][m * 6 + 5][j] = (_Float16)(m2hu * tc2);
        }
    }
    __syncthreads();

    // ---------------- layers 2..4: MFMA GEMM (48x256 @ 256x256) + fused tanh chain ----------------
    const int lane = tid & 63;
    const int w    = tid >> 6;        // wave id: owns cols [w*64, w*64+64)
    const int q    = lane >> 4;       // quarter
    const int r16  = lane & 15;

    int cur = 0;
    for (int l = 0; l < 3; ++l) {
        const int nxt = cur ^ 1;
        const _Float16* WL = Wp + l * 65536 + (w * 4) * 4096 + lane * 8;

        f32x4 acc[3][4];
        #pragma unroll
        for (int rt = 0; rt < 3; ++rt)
            #pragma unroll
            for (int ct = 0; ct < 4; ++ct)
                acc[rt][ct] = (f32x4){0.f, 0.f, 0.f, 0.f};

        #pragma unroll
        for (int ks = 0; ks < 8; ++ks) {
            half8 bfrag[4];
            #pragma unroll
            for (int ct = 0; ct < 4; ++ct)
                bfrag[ct] = *reinterpret_cast<const half8*>(WL + ct * 4096 + ks * 512);
            half8 afrag[3];
            #pragma unroll
            for (int rt = 0; rt < 3; ++rt)
                afrag[rt] = *reinterpret_cast<const half8*>(&buf[cur][rt * 16 + r16][ks * 32 + q * 8]);
            #pragma unroll
            for (int rt = 0; rt < 3; ++rt)
                #pragma unroll
                for (int ct = 0; ct < 4; ++ct)
                    acc[rt][ct] = __builtin_amdgcn_mfma_f32_16x16x32_f16(
                        afrag[rt], bfrag[ct], acc[rt][ct], 0, 0, 0);
        }

        // write C tiles (pre-activations) into buf[nxt]:
        // C layout: col = lane&15, row = (lane>>4)*4 + i
        #pragma unroll
        for (int rt = 0; rt < 3; ++rt)
            #pragma unroll
            for (int ct = 0; ct < 4; ++ct)
                #pragma unroll
                for (int i = 0; i < 4; ++i)
                    buf[nxt][rt * 16 + q * 4 + i][(w * 4 + ct) * 16 + r16] =
                        (_Float16)acc[rt][ct][i];
        __syncthreads();

        // elementwise tanh-chain on buf[nxt], in place: thread owns (sample s, cols c8..c8+7)
        {
            const int s  = tid >> 5;
            const int c8 = (tid & 31) * 8;
            const float* bb = (l == 0) ? b1 : (l == 1) ? b2 : b3;
            half8 z0 = *reinterpret_cast<const half8*>(&buf[nxt][s * 6 + 0][c8]);
            half8 z1 = *reinterpret_cast<const half8*>(&buf[nxt][s * 6 + 1][c8]);
            half8 z2 = *reinterpret_cast<const half8*>(&buf[nxt][s * 6 + 2][c8]);
            half8 z3 = *reinterpret_cast<const half8*>(&buf[nxt][s * 6 + 3][c8]);
            half8 z4 = *reinterpret_cast<const half8*>(&buf[nxt][s * 6 + 4][c8]);
            half8 z5 = *reinterpret_cast<const half8*>(&buf[nxt][s * 6 + 5][c8]);
            half8 o0, o1, o2, o3, o4, o5;
            #pragma unroll
            for (int e = 0; e < 8; ++e) {
                float Z   = (float)z0[e] + bb[c8 + e];
                float T0  = (float)z1[e];
                float T1  = (float)z2[e];
                float T2  = (float)z3[e];
                float Sab = (float)z4[e];
                float Sc  = (float)z5[e];
                float h  = tanh_fast(Z);
                float up = 1.0f - h * h;
                float tab = 2.0f * T0 + 2.0f * T1 + T2;
                float m2hu = -2.0f * h * up;
                o0[e] = (_Float16)h;
                o1[e] = (_Float16)(up * T0);
                o2[e] = (_Float16)(up * T1);
                o3[e] = (_Float16)(up * T2);
                o4[e] = (_Float16)fmaf(up, Sab, m2hu * tab * tab);
                o5[e] = (_Float16)fmaf(up, Sc,  m2hu * T2 * T2);
            }
            *reinterpret_cast<half8*>(&buf[nxt][s * 6 + 0][c8]) = o0;
            *reinterpret_cast<half8*>(&buf[nxt][s * 6 + 1][c8]) = o1;
            *reinterpret_cast<half8*>(&buf[nxt][s * 6 + 2][c8]) = o2;
            *reinterpret_cast<half8*>(&buf[nxt][s * 6 + 3][c8]) = o3;
            *reinterpret_cast<half8*>(&buf[nxt][s * 6 + 4][c8]) = o4;
            *reinterpret_cast<half8*>(&buf[nxt][s * 6 + 5][c8]) = o5;
        }
        __syncthreads();
        cur = nxt;
    }

    // ---------------- final layer: OUTS[48][5] = buf[cur] @ W4 (+b4 on primal rows) ----------------
    if (tid < RROWS * 5) {
        const int r = tid / 5;
        const int c = tid - r * 5;
        float s = 0.0f;
        for (int k = 0; k < HID; k += 8) {
            half8 av = *reinterpret_cast<const half8*>(&buf[cur][r][k]);
            #pragma unroll
            for (int jj = 0; jj < 8; ++jj)
                s = fmaf((float)av[jj], W4[(k + jj) * 5 + c], s);
        }
        if (r % 6 == 0) s += b4[c];
        OUTS[r][c] = s;
    }
    if (tid == 0) { rsum[0] = 0.0f; rsum[1] = 0.0f; }
    __syncthreads();

    // ---------------- NS residuals + block reduction ----------------
    if (tid < MWG) {
        const int m = tid;
        const int rb = m * 6;
        float u   = OUTS[rb + 0][0];
        float v   = OUTS[rb + 0][1];
        float w_  = OUTS[rb + 0][2];
        float rho = OUTS[rb + 0][3];
        const float* tg = target + (size_t)(base + m) * 3;
        float d0 = u - tg[0], d1 = v - tg[1], d2 = w_ - tg[2];
        float dpart = d0 * d0 + d1 * d1 + d2 * d2;

        float ug0 = OUTS[rb + 1][0], vg0 = OUTS[rb + 1][1], wg0 = OUTS[rb + 1][2], pg0 = OUTS[rb + 1][4];
        float ug1 = OUTS[rb + 2][0], vg1 = OUTS[rb + 2][1], wg1 = OUTS[rb + 2][2], pg1 = OUTS[rb + 2][4];
        float ug2 = OUTS[rb + 3][0], vg2 = OUTS[rb + 3][1], wg2 = OUTS[rb + 3][2];

        // polarization: h_k[0]+h_k[1] = 1/4 * (q_ab[k] - q_c[k])
        float hu = 0.25f * (OUTS[rb + 4][0] - OUTS[rb + 5][0]);
        float hv = 0.25f * (OUTS[rb + 4][1] - OUTS[rb + 5][1]);
        float hw = 0.25f * (OUTS[rb + 4][2] - OUTS[rb + 5][2]);

        float mx = rho * (ug2 + u * ug0 + v * ug1) + pg0 - MU_F * hu;
        float my = rho * (vg2 + u * vg0 + v * vg1) + pg1 - MU_F * hv;
        float mz = rho * (wg2 + u * wg0 + v * wg1)       - MU_F * hw;
        float ppart = mx * mx + my * my + mz * mz;

        atomicAdd(&rsum[0], dpart);
        atomicAdd(&rsum[1], ppart);
    }
    __syncthreads();
    if (tid == 0) {
        atomicAdd(&out_acc[1], rsum[0]);
        atomicAdd(&out_acc[2], rsum[1]);
    }
}

extern "C" void kernel_launch(void* const* d_in, const int* in_sizes, int n_in,
                              void* d_out, int out_size, void* d_ws, size_t ws_size,
                              hipStream_t stream) {
    const float* x  = (const float*)d_in[0];
    const float* tg = (const float*)d_in[1];
    const float* W0 = (const float*)d_in[2];
    const float* b0 = (const float*)d_in[3];
    const float* W1 = (const float*)d_in[4];
    const float* b1 = (const float*)d_in[5];
    const float* W2 = (const float*)d_in[6];
    const float* b2 = (const float*)d_in[7];
    const float* W3 = (const float*)d_in[8];
    const float* b3 = (const float*)d_in[9];
    const float* W4 = (const float*)d_in[10];
    const float* b4 = (const float*)d_in[11];
    float* out = (float*)d_out;
    _Float16* wp = (_Float16*)d_ws;   // 3*65536 f16 = 384 KB

    zero_out_kernel<<<dim3(1), dim3(64), 0, stream>>>(out);
    pack_w_kernel<<<dim3(768), dim3(256), 0, stream>>>(W1, W2, W3, wp);
    pinn_loss_kernel<<<dim3(NSAMP / MWG), dim3(256), 0, stream>>>(
        x, tg, W0, b0, b1, b2, b3, W4, b4, wp, out);
    finalize_kernel<<<dim3(1), dim3(64), 0, stream>>>(out);
}

// Round 3
// 198.951 us; speedup vs baseline: 8.8160x; 2.0008x over previous
//
#include <hip/hip_runtime.h>

#define NSAMP 65536
#define HID 256
#define MWG 16           // samples per workgroup
#define RROWS 96         // 6 channels * MWG, row = ch*16 + m  (channel-major)
#define LDA 264          // padded LDS row stride (f16 elems)
#define MU_F 1.7894e-05f
#define NBLK (NSAMP / MWG)

typedef _Float16 half8 __attribute__((ext_vector_type(8)));
typedef float f32x4 __attribute__((ext_vector_type(4)));

__device__ __forceinline__ float fast_rcp(float a) {
    float r; asm("v_rcp_f32 %0, %1" : "=v"(r) : "v"(a)); return r;
}
// tanh(z) = 1 - 2/(exp(2z)+1); inf-safe at both ends
__device__ __forceinline__ float tanh_fast(float z) {
    float e = __expf(2.0f * z);
    return fmaf(-2.0f, fast_rcp(e + 1.0f), 1.0f);
}

__global__ void zero_out_kernel(float* out) {
    if (threadIdx.x < 2) out[1 + threadIdx.x] = 0.0f;
}

__global__ void finalize_kernel(float* out) {
    if (threadIdx.x == 0) {
        float data = out[1] * (1.0f / (3.0f * (float)NSAMP));
        float phys = out[2] * (1.0f / (float)NSAMP);
        out[0] = data + phys;
        out[1] = data;
        out[2] = phys;
    }
}

// Pack W1..W3 (fp32 256x256 [k][col]) into f16 B-fragment order:
// offset = jt*4096 + ks*512 + lane*8 + j  ->  W[k*256+col],
// k = ks*32 + (lane>>4)*8 + j, col = jt*16 + (lane&15).
// Then W4 (256x5, zero-padded to 16 cols) at offset 196608: ks*512 + lane*8 + j.
__global__ __launch_bounds__(256)
void pack_w_kernel(const float* __restrict__ W1, const float* __restrict__ W2,
                   const float* __restrict__ W3, const float* __restrict__ W4,
                   _Float16* __restrict__ ws) {
    const int gid = blockIdx.x * 256 + threadIdx.x;   // grid covers 200704
    if (gid < 196608) {
        const int layer = gid >> 16;
        const int idx = gid & 65535;
        const int j    = idx & 7;
        const int lane = (idx >> 3) & 63;
        const int ks   = (idx >> 9) & 7;
        const int jt   = idx >> 12;
        const int k   = ks * 32 + (lane >> 4) * 8 + j;
        const int col = jt * 16 + (lane & 15);
        const float* W = (layer == 0) ? W1 : (layer == 1) ? W2 : W3;
        ws[gid] = (_Float16)W[k * HID + col];
    } else {
        const int idx = gid - 196608;                 // 0..4095
        const int j    = idx & 7;
        const int lane = (idx >> 3) & 63;
        const int ks   = idx >> 9;
        const int k   = ks * 32 + (lane >> 4) * 8 + j;
        const int col = lane & 15;
        ws[gid] = (_Float16)((col < 5) ? W4[k * 5 + col] : 0.0f);
    }
}

// Channels: 0=h, 1=t0, 2=t1, 3=t2, 4=s_ab (dir 2,2,1,0), 5=s_c (dir 0,0,1,0)
__global__ __launch_bounds__(256, 3)
void pinn_loss_kernel(const float* __restrict__ x, const float* __restrict__ target,
                      const float* __restrict__ W0, const float* __restrict__ b0,
                      const float* __restrict__ b1, const float* __restrict__ b2,
                      const float* __restrict__ b3, const float* __restrict__ b4,
                      const _Float16* __restrict__ Wp, float* __restrict__ out_acc)
{
    __shared__ _Float16 buf[RROWS][LDA];   // activations, channel-major rows
    __shared__ float OUTS[RROWS][5];
    __shared__ float xs[MWG * 4];
    __shared__ float rsum[2];

    const int tid = threadIdx.x;
    const int base = blockIdx.x * MWG;
    if (tid < MWG * 4) xs[tid] = x[(size_t)base * 4 + tid];
    if (tid == 0) { rsum[0] = 0.0f; rsum[1] = 0.0f; }
    __syncthreads();

    // ---------------- layer 1: input(4) -> 256, elementwise init ----------------
    {
        const int j = tid;
        const float w0 = W0[j], w1 = W0[HID + j], w2 = W0[2 * HID + j], w3 = W0[3 * HID + j];
        const float bj = b0[j];
        const float tab = 2.0f * w0 + 2.0f * w1 + w2;
        const float tab2 = tab * tab;
        const float tc2 = w2 * w2;
        #pragma unroll
        for (int m = 0; m < MWG; ++m) {
            float z = fmaf(xs[4 * m], w0, fmaf(xs[4 * m + 1], w1,
                      fmaf(xs[4 * m + 2], w2, fmaf(xs[4 * m + 3], w3, bj))));
            float h = tanh_fast(z);
            float up = fmaf(-h, h, 1.0f);
            float m2hu = -2.0f * h * up;
            buf[0 * MWG + m][j] = (_Float16)h;
            buf[1 * MWG + m][j] = (_Float16)(up * w0);
            buf[2 * MWG + m][j] = (_Float16)(up * w1);
            buf[3 * MWG + m][j] = (_Float16)(up * w2);
            buf[4 * MWG + m][j] = (_Float16)(m2hu * tab2);
            buf[5 * MWG + m][j] = (_Float16)(m2hu * tc2);
        }
    }
    __syncthreads();

    const int lane = tid & 63;
    const int w    = tid >> 6;        // wave owns cols [w*64, w*64+64)
    const int q    = lane >> 4;
    const int r16  = lane & 15;
    const int colbase = w * 64;

    // ---------------- layers 2..4: MFMA + fused in-register tanh chain ----------------
    for (int l = 0; l < 3; ++l) {
        const _Float16* WL = Wp + l * 65536 + (w * 4) * 4096 + lane * 8;

        f32x4 acc[6][4];
        #pragma unroll
        for (int ch = 0; ch < 6; ++ch)
            #pragma unroll
            for (int ct = 0; ct < 4; ++ct)
                acc[ch][ct] = (f32x4){0.f, 0.f, 0.f, 0.f};

        #pragma unroll
        for (int ks = 0; ks < 8; ++ks) {
            half8 bfrag[4];
            #pragma unroll
            for (int ct = 0; ct < 4; ++ct)
                bfrag[ct] = *reinterpret_cast<const half8*>(WL + ct * 4096 + ks * 512);
            half8 afrag[6];
            #pragma unroll
            for (int ch = 0; ch < 6; ++ch)
                afrag[ch] = *reinterpret_cast<const half8*>(&buf[ch * MWG + r16][ks * 32 + q * 8]);
            #pragma unroll
            for (int ch = 0; ch < 6; ++ch)
                #pragma unroll
                for (int ct = 0; ct < 4; ++ct)
                    acc[ch][ct] = __builtin_amdgcn_mfma_f32_16x16x32_f16(
                        afrag[ch], bfrag[ct], acc[ch][ct], 0, 0, 0);
        }
        __syncthreads();   // all LDS reads of buf complete before overwrite

        // fused chain on f32 accumulators; C layout: col=lane&15, sample row=q*4+i
        const float* bb = (l == 0) ? b1 : (l == 1) ? b2 : b3;
        #pragma unroll
        for (int ct = 0; ct < 4; ++ct) {
            const int col = colbase + ct * 16 + r16;
            const float bv = bb[col];
            #pragma unroll
            for (int i = 0; i < 4; ++i) {
                const int m = q * 4 + i;
                float Z   = acc[0][ct][i] + bv;
                float T0  = acc[1][ct][i];
                float T1  = acc[2][ct][i];
                float T2  = acc[3][ct][i];
                float Sab = acc[4][ct][i];
                float Sc  = acc[5][ct][i];
                float h  = tanh_fast(Z);
                float up = fmaf(-h, h, 1.0f);
                float tab = fmaf(2.0f, T0 + T1, T2);
                float m2 = -2.0f * h * up;
                buf[0 * MWG + m][col] = (_Float16)h;
                buf[1 * MWG + m][col] = (_Float16)(up * T0);
                buf[2 * MWG + m][col] = (_Float16)(up * T1);
                buf[3 * MWG + m][col] = (_Float16)(up * T2);
                buf[4 * MWG + m][col] = (_Float16)fmaf(up, Sab, m2 * (tab * tab));
                buf[5 * MWG + m][col] = (_Float16)fmaf(up, Sc,  m2 * (T2 * T2));
            }
        }
        __syncthreads();
    }

    // ---------------- final layer via MFMA: wave w<3 handles channels {2w, 2w+1} ----------------
    if (w < 3) {
        const _Float16* WL4 = Wp + 196608 + lane * 8;
        f32x4 a4[2];
        a4[0] = (f32x4){0.f, 0.f, 0.f, 0.f};
        a4[1] = (f32x4){0.f, 0.f, 0.f, 0.f};
        #pragma unroll
        for (int ks = 0; ks < 8; ++ks) {
            half8 bf = *reinterpret_cast<const half8*>(WL4 + ks * 512);
            half8 af0 = *reinterpret_cast<const half8*>(&buf[(2 * w) * MWG + r16][ks * 32 + q * 8]);
            half8 af1 = *reinterpret_cast<const half8*>(&buf[(2 * w + 1) * MWG + r16][ks * 32 + q * 8]);
            a4[0] = __builtin_amdgcn_mfma_f32_16x16x32_f16(af0, bf, a4[0], 0, 0, 0);
            a4[1] = __builtin_amdgcn_mfma_f32_16x16x32_f16(af1, bf, a4[1], 0, 0, 0);
        }
        if (r16 < 5) {
            #pragma unroll
            for (int i = 0; i < 4; ++i) {
                OUTS[(2 * w)     * MWG + q * 4 + i][r16] = a4[0][i];
                OUTS[(2 * w + 1) * MWG + q * 4 + i][r16] = a4[1][i];
            }
        }
    }
    __syncthreads();

    // ---------------- NS residuals + block reduction ----------------
    if (tid < MWG) {
        const int m = tid;
        float u   = OUTS[0 * MWG + m][0] + b4[0];
        float v   = OUTS[0 * MWG + m][1] + b4[1];
        float w_  = OUTS[0 * MWG + m][2] + b4[2];
        float rho = OUTS[0 * MWG + m][3] + b4[3];
        const float* tg = target + (size_t)(base + m) * 3;
        float d0 = u - tg[0], d1 = v - tg[1], d2 = w_ - tg[2];
        float dpart = d0 * d0 + d1 * d1 + d2 * d2;

        float ug0 = OUTS[1 * MWG + m][0], vg0 = OUTS[1 * MWG + m][1], wg0 = OUTS[1 * MWG + m][2], pg0 = OUTS[1 * MWG + m][4];
        float ug1 = OUTS[2 * MWG + m][0], vg1 = OUTS[2 * MWG + m][1], wg1 = OUTS[2 * MWG + m][2], pg1 = OUTS[2 * MWG + m][4];
        float ug2 = OUTS[3 * MWG + m][0], vg2 = OUTS[3 * MWG + m][1], wg2 = OUTS[3 * MWG + m][2];

        // polarization: h_k[0]+h_k[1] = 1/4 * (q_ab[k] - q_c[k])
        float hu = 0.25f * (OUTS[4 * MWG + m][0] - OUTS[5 * MWG + m][0]);
        float hv = 0.25f * (OUTS[4 * MWG + m][1] - OUTS[5 * MWG + m][1]);
        float hw = 0.25f * (OUTS[4 * MWG + m][2] - OUTS[5 * MWG + m][2]);

        float mx = rho * (ug2 + u * ug0 + v * ug1) + pg0 - MU_F * hu;
        float my = rho * (vg2 + u * vg0 + v * vg1) + pg1 - MU_F * hv;
        float mz = rho * (wg2 + u * wg0 + v * wg1)       - MU_F * hw;
        float ppart = mx * mx + my * my + mz * mz;

        atomicAdd(&rsum[0], dpart);
        atomicAdd(&rsum[1], ppart);
    }
    __syncthreads();
    if (tid == 0) {
        atomicAdd(&out_acc[1], rsum[0]);
        atomicAdd(&out_acc[2], rsum[1]);
    }
}

extern "C" void kernel_launch(void* const* d_in, const int* in_sizes, int n_in,
                              void* d_out, int out_size, void* d_ws, size_t ws_size,
                              hipStream_t stream) {
    const float* x  = (const float*)d_in[0];
    const float* tg = (const float*)d_in[1];
    const float* W0 = (const float*)d_in[2];
    const float* b0 = (const float*)d_in[3];
    const float* W1 = (const float*)d_in[4];
    const float* b1 = (const float*)d_in[5];
    const float* W2 = (const float*)d_in[6];
    const float* b2 = (const float*)d_in[7];
    const float* W3 = (const float*)d_in[8];
    const float* b3 = (const float*)d_in[9];
    const float* W4 = (const float*)d_in[10];
    const float* b4 = (const float*)d_in[11];
    float* out = (float*)d_out;
    _Float16* wp = (_Float16*)d_ws;   // 200704 f16 = 392 KB packed W1..W4

    zero_out_kernel<<<dim3(1), dim3(64), 0, stream>>>(out);
    pack_w_kernel<<<dim3(784), dim3(256), 0, stream>>>(W1, W2, W3, W4, wp);
    pinn_loss_kernel<<<dim3(NBLK), dim3(256), 0, stream>>>(
        x, tg, W0, b0, b1, b2, b3, b4, wp, out);
    finalize_kernel<<<dim3(1), dim3(64), 0, stream>>>(out);
}